// Round 7
// baseline (211.062 us; speedup 1.0000x reference)
//
#include <hip/hip_runtime.h>

typedef __bf16 bf16;
typedef bf16  bf16x8 __attribute__((ext_vector_type(8)));
typedef bf16  bf16x4 __attribute__((ext_vector_type(4)));
typedef float f32x4  __attribute__((ext_vector_type(4)));

#define MFMA16(a, b, c) __builtin_amdgcn_mfma_f32_16x16x32_bf16((a), (b), (c), 0, 0, 0)
#define AS1 __attribute__((address_space(1)))
#define AS3 __attribute__((address_space(3)))

// async global->LDS, 16B per lane; LDS dest = (wave-uniform) base + lane*16
__device__ __forceinline__ void gld_lds16(const bf16* g, bf16* l) {
    __builtin_amdgcn_global_load_lds((AS1 void*)(g), (AS3 void*)(l), 16, 0, 0);
}

// XOR swizzle (GEMM tiles): [rows][32] 64B rows; logical chunk c of row r at c ^ ((r>>1)&3).
// Staging permutes the GLOBAL source: logical chunk = (lane&3) ^ ((lane>>3)&3).

// ---------------- fused fp32 -> bf16 casts (x + 4 weights, one dispatch) ----------------
__global__ __launch_bounds__(256) void cvt_all(const float* __restrict__ x,
                                               const float* __restrict__ Wq, const float* __restrict__ Wk,
                                               const float* __restrict__ Wv, const float* __restrict__ Wu,
                                               bf16* ox, bf16* oq, bf16* ok, bf16* ov, bf16* ou,
                                               float sq, float sk) {
    int bid = blockIdx.x;
    const float* src; bf16* dst; float sc; int base;
    if (bid < 4096) { src = x; dst = ox; sc = 1.0f; base = bid; }
    else {
        int w = (bid - 4096) >> 10; base = (bid - 4096) & 1023;
        switch (w) {
            case 0:  src = Wq; dst = oq; sc = sq;   break;
            case 1:  src = Wk; dst = ok; sc = sk;   break;
            case 2:  src = Wv; dst = ov; sc = 1.0f; break;
            default: src = Wu; dst = ou; sc = 1.0f; break;
        }
    }
    int idx = (base * 256 + threadIdx.x) * 4;
    float4 v = *(const float4*)(src + idx);
    bf16x4 o;
    o[0] = (bf16)(v.x * sc); o[1] = (bf16)(v.y * sc);
    o[2] = (bf16)(v.z * sc); o[3] = (bf16)(v.w * sc);
    *(bf16x4*)(dst + idx) = o;
}

// ---------------- shared NT-GEMM core: C[m,n] = sum_k A[m,k]*B[n,k] ----------------
// 128x128 tile, BK=32, K=1024. 256 threads = 4 waves (2x2, each 64x64 = 4x4 MFMA tiles).
__device__ __forceinline__ void gemm_core(const bf16* __restrict__ A, const bf16* __restrict__ B,
                                          int mBase, int nBase, bf16* As, bf16* Bs,
                                          f32x4 acc[4][4]) {
    const int tid = threadIdx.x;
    const int wave = tid >> 6, lane = tid & 63;
    const int g = lane >> 4, lr = lane & 15;
    const int wm = (wave & 1) << 6, wn = (wave >> 1) << 6;
    const int q = lane >> 2;
    const int cswz = ((lane & 3) ^ ((lane >> 3) & 3)) << 3;
    const int pcs  = (g ^ ((lr >> 1) & 3)) << 3;

    const int rb0 = wave << 4, rb1 = rb0 + 64;
    const bf16* a0 = A + (size_t)(mBase + rb0 + q) * 1024 + cswz;
    const bf16* a1 = A + (size_t)(mBase + rb1 + q) * 1024 + cswz;
    const bf16* b0 = B + (size_t)(nBase + rb0 + q) * 1024 + cswz;
    const bf16* b1 = B + (size_t)(nBase + rb1 + q) * 1024 + cswz;

    for (int k0 = 0; k0 < 1024; k0 += 32) {
        __syncthreads();
        gld_lds16(a0 + k0, As + rb0 * 32);
        gld_lds16(a1 + k0, As + rb1 * 32);
        gld_lds16(b0 + k0, Bs + rb0 * 32);
        gld_lds16(b1 + k0, Bs + rb1 * 32);
        __syncthreads();

        bf16x8 af[4], bfr[4];
#pragma unroll
        for (int i = 0; i < 4; i++)
            af[i] = *(const bf16x8*)&As[(wm + (i << 4) + lr) * 32 + pcs];
#pragma unroll
        for (int j = 0; j < 4; j++)
            bfr[j] = *(const bf16x8*)&Bs[(wn + (j << 4) + lr) * 32 + pcs];
#pragma unroll
        for (int i = 0; i < 4; i++)
#pragma unroll
            for (int j = 0; j < 4; j++)
                acc[i][j] = MFMA16(af[i], bfr[j], acc[i][j]);
    }
}

// ---------------- merged QKV GEMM (R6 epilogues, coalesced) ----------------
__global__ __launch_bounds__(256) void gemm_qkv(const bf16* __restrict__ X,
                                                const bf16* __restrict__ Wqk,  // [2048][1024]
                                                const bf16* __restrict__ Wv,
                                                bf16* __restrict__ Qo, bf16* __restrict__ Ko,
                                                bf16* __restrict__ Vto) {
    __shared__ bf16 As[128 * 32];
    __shared__ bf16 Bs[128 * 32];
    const int tid = threadIdx.x;
    const int wave = tid >> 6, lane = tid & 63;
    const int g = lane >> 4, lr = lane & 15;
    const int wm = (wave & 1) << 6, wn = (wave >> 1) << 6;
    const int my = blockIdx.y;
    const bool qk = (my < 16);

    const bf16* Ap = qk ? Wqk : X;
    const bf16* Bp = qk ? X   : Wv;
    const int mBase = qk ? my * 128 : blockIdx.x * 128;
    const int nBase = qk ? blockIdx.x * 128 : (my - 16) * 128;

    f32x4 acc[4][4] = {};
    gemm_core(Ap, Bp, mBase, nBase, As, Bs, acc);

    if (qk) {
#pragma unroll
        for (int i = 0; i < 4; i++) {
            int m0 = mBase + wm + (i << 4) + (g << 2);
            bf16* dst = (m0 >> 10) ? Ko : Qo;
            int feat = m0 & 1023;
            int h = feat >> 6, d = feat & 63;
#pragma unroll
            for (int j = 0; j < 4; j++) {
                int t = nBase + wn + (j << 4) + lr;
                int b = t >> 11, tl = t & 2047;
                bf16x4 v;
#pragma unroll
                for (int r = 0; r < 4; r++) v[r] = (bf16)acc[i][j][r];
                *(bf16x4*)&dst[(((size_t)((b << 4) + h) * 2048 + tl) << 6) + d] = v;
            }
        }
    } else {
#pragma unroll
        for (int i = 0; i < 4; i++) {
            int t0 = mBase + wm + (i << 4) + (g << 2);
            int b = t0 >> 11, tl = t0 & 2047;
#pragma unroll
            for (int j = 0; j < 4; j++) {
                int o = nBase + wn + (j << 4) + lr;
                int h = o >> 6, d = o & 63;
                bf16x4 v;
#pragma unroll
                for (int r = 0; r < 4; r++) v[r] = (bf16)acc[i][j][r];
                *(bf16x4*)&Vto[((size_t)(((b << 4) + h) << 6) + d) * 2048 + tl] = v;
            }
        }
    }
}

// ---------------- output GEMM (role-swapped): out = attn @ Wu^T + bu ----------------
__global__ __launch_bounds__(256) void gemm_out(const bf16* __restrict__ Wu, const bf16* __restrict__ A,
                                                const float* __restrict__ bias, float* __restrict__ out) {
    __shared__ bf16 As[128 * 32];
    __shared__ bf16 Bs[128 * 32];
    const int tid = threadIdx.x;
    const int wave = tid >> 6, lane = tid & 63;
    const int g = lane >> 4, lr = lane & 15;
    const int wm = (wave & 1) << 6, wn = (wave >> 1) << 6;
    const int mBase = blockIdx.y * 128, nBase = blockIdx.x * 128;

    f32x4 acc[4][4] = {};
    gemm_core(Wu, A, mBase, nBase, As, Bs, acc);

#pragma unroll
    for (int i = 0; i < 4; i++) {
        int o = mBase + wm + (i << 4) + (g << 2);
        float4 bv = *(const float4*)&bias[o];
#pragma unroll
        for (int j = 0; j < 4; j++) {
            int t = nBase + wn + (j << 4) + lr;
            float4 v;
            v.x = acc[i][j][0] + bv.x;
            v.y = acc[i][j][1] + bv.y;
            v.z = acc[i][j][2] + bv.z;
            v.w = acc[i][j][3] + bv.w;
            *(float4*)&out[((size_t)t << 10) + o] = v;
        }
    }
}

// ---------------- attention v3: LDS-traffic-minimized ----------------
// Per block: one (b,h), 64 Q rows. 1024 blocks, XCD swizzle kept (K/V L2-resident, R5).
// Q-frags in REGISTERS (loaded once from global). V-frags DIRECT from global (wave owns a
// d-half -> 16 fully-used cachelines per b128 instr, ~512MB L2 traffic total).
// QK: wave owns s-quarter x all 64 t -> each kf LDS read feeds 4 MFMAs.
// P: LDS roundtrip Ps[64][128] with 16B-chunk XOR (t&7) swizzle; barrier between write
// (C-layout: col t, s-groups of 4) and PV read (A-layout [t][s] b128) — cross-wave.
// PV: wave owns (t-half x d-half), accumulates over ALL s.
// lsum: VALU f32x4 accumulation + one endgame cross-wave LDS reduce.
// LDS/wave/s0: 4 kf + 8 pf b128 reads + 8 b64 writes ~= 192cyc (was 480 in R5).
__global__ __launch_bounds__(256, 4) void attn(const bf16* __restrict__ Q, const bf16* __restrict__ Kt,
                                               const bf16* __restrict__ Vt, bf16* __restrict__ O) {
    __shared__ bf16 Ks[2][128][32];   // 16KB [ks][s][d-half], GEMM-style swizzle
    __shared__ bf16 Ps[64][128];      // 16KB [t][s], chunk-XOR(t&7)
    float* Lbuf = (float*)&Ks[0][0][0];  // endgame alias [wave][64]

    const int tid = threadIdx.x;
    const int wave = tid >> 6, lane = tid & 63;
    const int g = lane >> 4, lr = lane & 15;
    const int q = lane >> 2;
    const int cswz = ((lane & 3) ^ ((lane >> 3) & 3)) << 3;
    const int pcs  = (g ^ ((lr >> 1) & 3)) << 3;
    const int lr7  = lr & 7;
    const int thalf = wave >> 1, dhalf = wave & 1;

    const int bid = blockIdx.x;
    const int bh = ((bid & 7) << 2) | (bid >> 8);   // XCD-affinity (R5: FETCH 70->12MB)
    const int qBase = ((bid >> 3) & 31) << 6;

    const bf16* Qg = Q + ((size_t)bh * 2048 + qBase) * 64;
    const bf16* Kg = Kt + (size_t)bh * 2048 * 64;
    const bf16* Vg = Vt + (size_t)bh * 64 * 2048;

    // Q fragments -> registers (B-layout: n=t -> row qBase+tt*16+lr, k=d=ks*32+g*8)
    bf16x8 qf[2][4];
#pragma unroll
    for (int ks = 0; ks < 2; ks++)
#pragma unroll
        for (int tt = 0; tt < 4; tt++)
            qf[ks][tt] = *(const bf16x8*)(Qg + ((tt << 4) + lr) * 64 + (ks << 5) + (g << 3));

    // P-write elem offsets (b64): chunk c = wave*4 + isub*2 + (g>>1), phys = c ^ lr7
    const int pw0 = ((((wave << 2) + (g >> 1))     ^ lr7) << 3) + ((g & 1) << 2);
    const int pw1 = ((((wave << 2) + 2 + (g >> 1)) ^ lr7) << 3) + ((g & 1) << 2);

    f32x4 oacc[2][2] = {};
    f32x4 lsumv[4] = {};

    for (int s0 = 0; s0 < 2048; s0 += 128) {
        __syncthreads();                 // b1: prior PV/P reads done everywhere
#pragma unroll
        for (int i = 0; i < 4; i++) {    // stage K chunk [2][128][32]
            int bi = (wave << 2) + i;
            int p = bi >> 3, rb = (bi & 7) << 4;
            gld_lds16(Kg + (size_t)(s0 + rb + q) * 64 + (p << 5) + cswz, &Ks[p][rb][0]);
        }
        __syncthreads();                 // b2: K visible

        // QK for this wave's s-quarter (s_local = wave*32 + isub*16 + g*4+r), all 64 t
#pragma unroll
        for (int isub = 0; isub < 2; isub++) {
            f32x4 sacc[4] = {};
#pragma unroll
            for (int ks = 0; ks < 2; ks++) {
                bf16x8 kf = *(const bf16x8*)&Ks[ks][(wave << 5) + (isub << 4) + lr][pcs];
#pragma unroll
                for (int tt = 0; tt < 4; tt++)
                    sacc[tt] = MFMA16(kf, qf[ks][tt], sacc[tt]);
            }
#pragma unroll
            for (int tt = 0; tt < 4; tt++) {
                f32x4 e;
                e[0] = __builtin_amdgcn_exp2f(sacc[tt][0]);
                e[1] = __builtin_amdgcn_exp2f(sacc[tt][1]);
                e[2] = __builtin_amdgcn_exp2f(sacc[tt][2]);
                e[3] = __builtin_amdgcn_exp2f(sacc[tt][3]);
                lsumv[tt] += e;
                bf16x4 pb;
                pb[0] = (bf16)e[0]; pb[1] = (bf16)e[1]; pb[2] = (bf16)e[2]; pb[3] = (bf16)e[3];
                *(bf16x4*)&Ps[(tt << 4) + lr][isub ? pw1 : pw0] = pb;
            }
        }
        __syncthreads();                 // b3: P visible block-wide

        // PV: this wave owns (t-half, d-half), all 128 s
#pragma unroll
        for (int ks2 = 0; ks2 < 4; ks2++) {
            bf16x8 vf[2], pf[2];
#pragma unroll
            for (int dd = 0; dd < 2; dd++)
                vf[dd] = *(const bf16x8*)(Vg + (size_t)((dhalf << 5) + (dd << 4) + lr) * 2048
                                          + s0 + (ks2 << 5) + (g << 3));
#pragma unroll
            for (int tt = 0; tt < 2; tt++)
                pf[tt] = *(const bf16x8*)&Ps[(thalf << 5) + (tt << 4) + lr]
                                            [(((ks2 << 2) + g) ^ lr7) << 3];
#pragma unroll
            for (int tt = 0; tt < 2; tt++)
#pragma unroll
                for (int dd = 0; dd < 2; dd++)
                    oacc[tt][dd] = MFMA16(pf[tt], vf[dd], oacc[tt][dd]);
        }
    }

    // ---- endgame: cross-wave lsum reduce, then normalize + store ----
    float lpart[4];
#pragma unroll
    for (int tt = 0; tt < 4; tt++) {
        lpart[tt] = (lsumv[tt][0] + lsumv[tt][1]) + (lsumv[tt][2] + lsumv[tt][3]);
        lpart[tt] += __shfl_xor(lpart[tt], 16, 64);
        lpart[tt] += __shfl_xor(lpart[tt], 32, 64);
    }
    __syncthreads();                     // Ks dead -> Lbuf
    if (g == 0) {
#pragma unroll
        for (int tt = 0; tt < 4; tt++)
            Lbuf[(wave << 6) + (tt << 4) + lr] = lpart[tt];
    }
    __syncthreads();

    const int b = bh >> 4, h = bh & 15;
#pragma unroll
    for (int tt = 0; tt < 2; tt++) {
        float linv[4];
#pragma unroll
        for (int r = 0; r < 4; r++) {
            int t = (thalf << 5) + (tt << 4) + (g << 2) + r;
            linv[r] = 1.0f / (((Lbuf[t] + Lbuf[64 + t]) + (Lbuf[128 + t] + Lbuf[192 + t])));
        }
#pragma unroll
        for (int dd = 0; dd < 2; dd++)
#pragma unroll
            for (int r = 0; r < 4; r++) {
                int t = qBase + (thalf << 5) + (tt << 4) + (g << 2) + r;
                int col = (h << 6) + (dhalf << 5) + (dd << 4) + lr;
                O[(((size_t)(b * 2048 + t)) << 10) + col] = (bf16)(oacc[tt][dd][r] * linv[r]);
            }
    }
}

extern "C" void kernel_launch(void* const* d_in, const int* in_sizes, int n_in,
                              void* d_out, int out_size, void* d_ws, size_t ws_size,
                              hipStream_t stream) {
    const float* x  = (const float*)d_in[0];
    const float* Wq = (const float*)d_in[1];
    const float* Wk = (const float*)d_in[2];
    const float* Wv = (const float*)d_in[3];
    const float* Wu = (const float*)d_in[4];
    const float* bu = (const float*)d_in[5];
    float* out = (float*)d_out;

    char* ws = (char*)d_ws;
    bf16* xbf  = (bf16*)(ws);                      // 8MB; reused as attn output after QKV GEMM
    bf16* wqbf = (bf16*)(ws + ((size_t)8  << 20)); // wq+wk contiguous = stacked [2048][1024]
    bf16* wkbf = (bf16*)(ws + ((size_t)10 << 20));
    bf16* wvbf = (bf16*)(ws + ((size_t)12 << 20));
    bf16* wubf = (bf16*)(ws + ((size_t)14 << 20));
    bf16* Qb   = (bf16*)(ws + ((size_t)16 << 20)); // [b,h,t,d] 8MB
    bf16* Kb   = (bf16*)(ws + ((size_t)24 << 20)); // [b,h,t,d] 8MB
    bf16* Vtb  = (bf16*)(ws + ((size_t)32 << 20)); // [b,h,d,t] 8MB
    bf16* attnO = xbf;                             // overlay: x dead after gemm_qkv

    const float iscale_k = 0.17677669529663687f;   // 1024^-0.25
    const float iscale_q = 0.25503540109f;         // 1024^-0.25 * log2(e) -> scores in log2 domain

    cvt_all<<<8192, 256, 0, stream>>>(x, Wq, Wk, Wv, Wu, xbf, wqbf, wkbf, wvbf, wubf,
                                      iscale_q, iscale_k);

    gemm_qkv<<<dim3(32, 24), 256, 0, stream>>>(xbf, wqbf, wvbf, Qb, Kb, Vtb);
    attn<<<dim3(1024), 256, 0, stream>>>(Qb, Kb, Vtb, attnO);
    gemm_out<<<dim3(32, 8), 256, 0, stream>>>(wubf, attnO, bu, out);
}